// Round 11
// baseline (1693.196 us; speedup 1.0000x reference)
//
#include <hip/hip_runtime.h>
#include <math.h>

// ---------------------------------------------------------------------------
// VQ-VAE forward. R11 = R10 (1.651 ms, PASSED) + two R9 fusions REPAIRED:
//  1. BN stats fused into conv epilogues with DOUBLE partials (R9 bug: fp32
//     partials -> ~1e-5 var error -> idx flips). nn-sum in double, shfl_xor
//     double reduce over 16 px lanes, double atomics into part[].
//  2. bn+residual+relu fused into down/up STAGING (elementwise-identical to
//     bn_res_relu), with alias-free buffer plan. up1 keeps separate
//     bn_res_relu (no alias-free full-size output region exists).
// Removes 8 bn_part + 3 bn_res_relu full-tensor passes (~160 us + gaps).
// conv math (conv36, 6-term SPLIT=3 enc / 3-term SPLIT=2 dec) unchanged.
// ---------------------------------------------------------------------------

#define RE_SIZE 786432

typedef float f32x4 __attribute__((ext_vector_type(4)));
typedef short bf16x8 __attribute__((ext_vector_type(8)));
typedef short bf16x4 __attribute__((ext_vector_type(4)));

__device__ __forceinline__ unsigned short f2bf(float f) {
  unsigned u = __float_as_uint(f);
  return (unsigned short)((u + 0x7fffu + ((u >> 16) & 1u)) >> 16);   // RNE
}
__device__ __forceinline__ float bf2f(unsigned short h) {
  return __uint_as_float(((unsigned)h) << 16);
}
__device__ __forceinline__ void split3(float v, unsigned short& a,
                                       unsigned short& b, unsigned short& c) {
  a = f2bf(v); float r = v - bf2f(a);
  b = f2bf(r); r -= bf2f(b);
  c = f2bf(r);
}

// ===== fused epilogue: store + BN partial stats (DOUBLE partials) ===========
#define CONV_EPILOGUE_STATS(OUTBASE, ROWSTRIDE, CHSTRIDE)                      \
  {                                                                            \
    double sA[2][4], qA[2][4];                                                 \
    _Pragma("unroll") for (int a = 0; a < 2; ++a)                              \
      _Pragma("unroll") for (int r = 0; r < 4; ++r) { sA[a][r] = 0.0; qA[a][r] = 0.0; } \
    _Pragma("unroll") for (int mt2 = 0; mt2 < 2; ++mt2) {                      \
      int co0 = (wv * 2 + mt2) * 16 + q * 4;                                   \
      _Pragma("unroll") for (int nn = 0; nn < 8; ++nn) {                       \
        long pxoff = (OUTBASE) + (long)nn * (ROWSTRIDE);                       \
        _Pragma("unroll") for (int r = 0; r < 4; ++r) {                        \
          float v = acc[mt2][nn][r] + bias[co0 + r];                           \
          out[pxoff + (long)(co0 + r) * (CHSTRIDE)] = v;                       \
          sA[mt2][r] += (double)v; qA[mt2][r] += (double)v * (double)v;        \
        }                                                                      \
      }                                                                        \
    }                                                                          \
    _Pragma("unroll") for (int m = 1; m < 16; m <<= 1)                         \
      _Pragma("unroll") for (int a = 0; a < 2; ++a)                            \
        _Pragma("unroll") for (int r = 0; r < 4; ++r) {                        \
          sA[a][r] += __shfl_xor(sA[a][r], m);                                 \
          qA[a][r] += __shfl_xor(qA[a][r], m);                                 \
        }                                                                      \
    if (c15 == 0) {                                                            \
      _Pragma("unroll") for (int a = 0; a < 2; ++a)                            \
        _Pragma("unroll") for (int r = 0; r < 4; ++r) {                        \
          int co = (wv * 2 + a) * 16 + q * 4 + r;                              \
          atomicAdd(&part[(slice * 128 + co) * 2 + 0], sA[a][r]);              \
          atomicAdd(&part[(slice * 128 + co) * 2 + 1], qA[a][r]);              \
        }                                                                      \
    }                                                                          \
  }

// ---------------- fused enc_in∘conv1 weights, A-frag order, K=64(36) --------
__global__ __launch_bounds__(256) void weff_kernel(
    const float* __restrict__ w3, const float* __restrict__ ew,
    const float* __restrict__ eb, unsigned short* __restrict__ f0,
    unsigned short* __restrict__ f1, unsigned short* __restrict__ f2) {
  int id = blockIdx.x * 256 + threadIdx.x;        // 8192
  int j = id & 7, lane = (id >> 3) & 63, mt = (id >> 9) & 7, kc = id >> 12;
  int co = mt * 16 + (lane & 15);
  int q = lane >> 4;
  int k = kc * 32 + q * 8 + j;
  int t = k >> 2, c = k & 3;
  float v = 0.f;
  if (t <= 8) {
    double acc = 0.0;
    for (int ci = 0; ci < 128; ++ci) {
      double wv = (double)w3[((long)co * 128 + ci) * 9 + t];
      double xv = (c < 3) ? (double)ew[ci * 3 + c] : (double)eb[ci];
      acc += wv * xv;
    }
    v = (float)acc;
  }
  unsigned short a, b, cc; split3(v, a, b, cc);
  f0[id] = a; f1[id] = b; f2[id] = cc;
}

// ---------------- encoder conv1: x(+ones) -> 128, K=36, 6-term MFMA ---------
__global__ __launch_bounds__(256) void conv36_mfma_kernel(
    const float* __restrict__ xin, const unsigned short* __restrict__ f0,
    const unsigned short* __restrict__ f1, const unsigned short* __restrict__ f2,
    const float* __restrict__ bias, float* __restrict__ out,
    double* __restrict__ part, int H, int W) {
  __shared__ __align__(16) unsigned short s_x[3][720];   // [y10][x18][ch4]
  int tid = threadIdx.x, wv = tid >> 6, lane = tid & 63;
  int q = lane >> 4, c15 = lane & 15;
  int tilesX = W >> 4;
  int tx0 = (blockIdx.x % tilesX) << 4;
  int ty0 = (blockIdx.x / tilesX) << 3;
  int n = blockIdx.z;
  int slice = blockIdx.x & 7;
  long HWl = (long)H * W;
  long ibase = (long)n * 128 * HWl;
  long xbase = (long)n * 3 * HWl;
  f32x4 acc[2][8];
#pragma unroll
  for (int a = 0; a < 2; ++a)
#pragma unroll
    for (int b = 0; b < 8; ++b) acc[a][b] = (f32x4){0.f, 0.f, 0.f, 0.f};

  for (int l = tid; l < 180; l += 256) {
    int y = l / 18, x = l % 18;
    int gy = ty0 + y - 1, gx = tx0 + x - 1;
    float v[4] = {0.f, 0.f, 0.f, 0.f};
    if ((unsigned)gy < (unsigned)H && (unsigned)gx < (unsigned)W) {
      const float* xp = xin + xbase + (long)gy * W + gx;
      v[0] = xp[0]; v[1] = xp[HWl]; v[2] = xp[2 * HWl]; v[3] = 1.f;
    }
    bf16x4 s0, s1, s2;
#pragma unroll
    for (int c = 0; c < 4; ++c) {
      unsigned short h0, h1, h2; split3(v[c], h0, h1, h2);
      s0[c] = (short)h0; s1[c] = (short)h1; s2[c] = (short)h2;
    }
    *(bf16x4*)(s_x[0] + l * 4) = s0;
    *(bf16x4*)(s_x[1] + l * 4) = s1;
    *(bf16x4*)(s_x[2] + l * 4) = s2;
  }
  __syncthreads();

#pragma unroll
  for (int kc = 0; kc < 2; ++kc) {
    bf16x8 a0[2], a1[2], a2[2];
#pragma unroll
    for (int m = 0; m < 2; ++m) {
      long fi = (long)(kc * 8 + 2 * wv + m) * 64 + lane;
      a0[m] = ((const bf16x8*)f0)[fi];
      a1[m] = ((const bf16x8*)f1)[fi];
      a2[m] = ((const bf16x8*)f2)[fi];
    }
    int ta = kc * 8 + 2 * q; if (ta > 8) ta = 8;   // clamped taps carry w=0
    int tb = ta + 1;         if (tb > 8) tb = 8;
    int pa_d = (ta / 3) * 18 + ta % 3;
    int pb_d = (tb / 3) * 18 + tb % 3;
#pragma unroll
    for (int nn = 0; nn < 8; ++nn) {
      int pa = (nn * 18 + c15 + pa_d) * 4;
      int pb = (nn * 18 + c15 + pb_d) * 4;
      bf16x8 b0, b1v, b2;
      bf16x4 lo, hi;
      lo = *(const bf16x4*)(s_x[0] + pa); hi = *(const bf16x4*)(s_x[0] + pb);
#pragma unroll
      for (int i = 0; i < 4; ++i) { b0[i] = lo[i]; b0[4 + i] = hi[i]; }
      lo = *(const bf16x4*)(s_x[1] + pa); hi = *(const bf16x4*)(s_x[1] + pb);
#pragma unroll
      for (int i = 0; i < 4; ++i) { b1v[i] = lo[i]; b1v[4 + i] = hi[i]; }
      lo = *(const bf16x4*)(s_x[2] + pa); hi = *(const bf16x4*)(s_x[2] + pb);
#pragma unroll
      for (int i = 0; i < 4; ++i) { b2[i] = lo[i]; b2[4 + i] = hi[i]; }
#pragma unroll
      for (int m = 0; m < 2; ++m) {
        acc[m][nn] = __builtin_amdgcn_mfma_f32_16x16x32_bf16(a0[m], b0, acc[m][nn], 0, 0, 0);
        acc[m][nn] = __builtin_amdgcn_mfma_f32_16x16x32_bf16(a0[m], b1v, acc[m][nn], 0, 0, 0);
        acc[m][nn] = __builtin_amdgcn_mfma_f32_16x16x32_bf16(a1[m], b0, acc[m][nn], 0, 0, 0);
        acc[m][nn] = __builtin_amdgcn_mfma_f32_16x16x32_bf16(a0[m], b2, acc[m][nn], 0, 0, 0);
        acc[m][nn] = __builtin_amdgcn_mfma_f32_16x16x32_bf16(a1[m], b1v, acc[m][nn], 0, 0, 0);
        acc[m][nn] = __builtin_amdgcn_mfma_f32_16x16x32_bf16(a2[m], b0, acc[m][nn], 0, 0, 0);
      }
    }
  }
  long ob = ibase + (long)ty0 * W + tx0 + c15;
  CONV_EPILOGUE_STATS(ob, W, HWl)
}

// ---------------- conv3x3 weight pre-split (A-frag order, 3 levels) ---------
__global__ __launch_bounds__(256) void wsplit_kernel(
    const float* __restrict__ w, unsigned short* __restrict__ w0,
    unsigned short* __restrict__ w1, unsigned short* __restrict__ w2) {
  int id = blockIdx.x * 256 + threadIdx.x;        // 576 blocks
  int j = id & 7, lane = (id >> 3) & 63, rest = id >> 9;
  int mt = rest & 7, rest2 = rest >> 3;
  int tap = rest2 % 9, cc = rest2 / 9;
  int co = mt * 16 + (lane & 15);
  int ci = cc * 32 + (lane >> 4) * 8 + j;
  float v = w[((long)co * 128 + ci) * 9 + tap];
  unsigned short a, b, c; split3(v, a, b, c);
  w0[id] = a; w1[id] = b; w2[id] = c;
}

// ---------------- down-conv weight pre-split (3 levels) ---------------------
__global__ __launch_bounds__(256) void wsplit4_kernel(
    const float* __restrict__ w, unsigned short* __restrict__ w0,
    unsigned short* __restrict__ w1, unsigned short* __restrict__ w2) {
  int id = blockIdx.x * 256 + threadIdx.x;        // 1024 blocks
  int j = id & 7, lane = (id >> 3) & 63;
  int mt = (id >> 9) & 7, pair = (id >> 12) & 7, cc = id >> 15;
  int q = lane >> 4;
  int tap = pair * 2 + (q >> 1);
  int ky = tap >> 2, kx = tap & 3;
  int co = mt * 16 + (lane & 15);
  int ci = cc * 16 + (q & 1) * 8 + j;
  float v = w[((long)co * 128 + ci) * 16 + ky * 4 + kx];
  unsigned short a, b, c; split3(v, a, b, c);
  w0[id] = a; w1[id] = b; w2[id] = c;
}

// ---------------- up-conv (convT) weight pre-split (2 levels) ---------------
__global__ __launch_bounds__(256) void wsplitT_kernel(
    const float* __restrict__ w, unsigned short* __restrict__ w0,
    unsigned short* __restrict__ w1) {
  int id = blockIdx.x * 256 + threadIdx.x;        // 1024 blocks
  int jj = id & 7, lane = (id >> 3) & 63;
  int mt = (id >> 9) & 7, j = (id >> 12) & 3, cls = (id >> 14) & 3, cc = id >> 16;
  int py = cls >> 1, px = cls & 1, jy = j >> 1, jx = j & 1;
  int ky = py ? (jy ? 2 : 0) : (jy ? 3 : 1);
  int kx = px ? (jx ? 2 : 0) : (jx ? 3 : 1);
  int co = mt * 16 + (lane & 15);
  int ci = cc * 32 + (lane >> 4) * 8 + jj;
  float v = w[((long)ci * 128 + co) * 16 + ky * 4 + kx];
  unsigned short h = f2bf(v);
  w0[id] = h;
  w1[id] = f2bf(v - bf2f(h));
}

// ---------------- conv 3x3 s1 p1, 128->128, +bias +fused stats --------------
// IMODE: 0 raw input; 1 bn+relu fused on staged input. SPLIT: 2 or 3.
template<int IMODE, int SPLIT>
__global__ __launch_bounds__(256) void conv3x3_mfma_kernel(
    const float* __restrict__ in, const unsigned short* __restrict__ w0s,
    const unsigned short* __restrict__ w1s, const unsigned short* __restrict__ w2s,
    const float* __restrict__ bias, float* __restrict__ out, int H, int W,
    const float2* __restrict__ mr, double* __restrict__ part) {
  __shared__ __align__(16) unsigned short s_x[SPLIT][5760];
  int tid = threadIdx.x, wv = tid >> 6, lane = tid & 63;
  int q = lane >> 4, c15 = lane & 15;
  int tilesX = W >> 4;
  int tx0 = (blockIdx.x % tilesX) << 4;
  int ty0 = (blockIdx.x / tilesX) << 3;
  int n = blockIdx.z;
  int slice = blockIdx.x & 7;
  long HWl = (long)H * W;
  long ibase = (long)n * 128 * HWl;
  f32x4 acc[2][8];
#pragma unroll
  for (int a = 0; a < 2; ++a)
#pragma unroll
    for (int b = 0; b < 8; ++b) acc[a][b] = (f32x4){0.f, 0.f, 0.f, 0.f};

  for (int cc = 0; cc < 4; ++cc) {
    __syncthreads();
    for (int l = tid; l < 720; l += 256) {
      int cig = l / 180, px = l % 180;
      int y = px / 18, x = px % 18;
      int gy = ty0 + y - 1, gx = tx0 + x - 1;
      float v[8];
      if ((unsigned)gy < (unsigned)H && (unsigned)gx < (unsigned)W) {
        const float* ip = in + ibase + (long)(cc * 32 + cig * 8) * HWl
                          + (long)gy * W + gx;
#pragma unroll
        for (int c = 0; c < 8; ++c) v[c] = ip[(long)c * HWl];
        if (IMODE == 1) {
#pragma unroll
          for (int c = 0; c < 8; ++c) {
            float2 s = mr[cc * 32 + cig * 8 + c];
            v[c] = fmaxf((v[c] - s.x) * s.y, 0.f);
          }
        }
      } else {
#pragma unroll
        for (int c = 0; c < 8; ++c) v[c] = 0.f;
      }
      bf16x8 sv[SPLIT];
#pragma unroll
      for (int c = 0; c < 8; ++c) {
        unsigned short h0 = f2bf(v[c]); float r = v[c] - bf2f(h0);
        unsigned short h1 = f2bf(r);
        sv[0][c] = (short)h0; sv[1][c] = (short)h1;
        if (SPLIT == 3) { r -= bf2f(h1); sv[2][c] = (short)f2bf(r); }
      }
#pragma unroll
      for (int s = 0; s < SPLIT; ++s) *(bf16x8*)(s_x[s] + l * 8) = sv[s];
    }
    __syncthreads();

    for (int tap = 0; tap < 9; ++tap) {
      int dy = tap / 3, dx = tap % 3;
      long fbase = (long)((cc * 9 + tap) * 8) * 64;
      bf16x8 a0[2], a1[2], a2[2];
#pragma unroll
      for (int m = 0; m < 2; ++m) {
        long fi = fbase + (2 * wv + m) * 64 + lane;
        a0[m] = ((const bf16x8*)w0s)[fi];
        a1[m] = ((const bf16x8*)w1s)[fi];
        if (SPLIT == 3) a2[m] = ((const bf16x8*)w2s)[fi];
      }
      int xoff = (q * 180 + dy * 18 + c15 + dx) * 8;
#pragma unroll
      for (int nn = 0; nn < 8; ++nn) {
        bf16x8 b0 = *(const bf16x8*)(s_x[0] + xoff + nn * 144);
        bf16x8 b1v = *(const bf16x8*)(s_x[1] + xoff + nn * 144);
#pragma unroll
        for (int m = 0; m < 2; ++m) {
          acc[m][nn] = __builtin_amdgcn_mfma_f32_16x16x32_bf16(a0[m], b0, acc[m][nn], 0, 0, 0);
          acc[m][nn] = __builtin_amdgcn_mfma_f32_16x16x32_bf16(a0[m], b1v, acc[m][nn], 0, 0, 0);
          acc[m][nn] = __builtin_amdgcn_mfma_f32_16x16x32_bf16(a1[m], b0, acc[m][nn], 0, 0, 0);
        }
        if (SPLIT == 3) {
          bf16x8 b2 = *(const bf16x8*)(s_x[2] + xoff + nn * 144);
#pragma unroll
          for (int m = 0; m < 2; ++m) {
            acc[m][nn] = __builtin_amdgcn_mfma_f32_16x16x32_bf16(a0[m], b2, acc[m][nn], 0, 0, 0);
            acc[m][nn] = __builtin_amdgcn_mfma_f32_16x16x32_bf16(a1[m], b1v, acc[m][nn], 0, 0, 0);
            acc[m][nn] = __builtin_amdgcn_mfma_f32_16x16x32_bf16(a2[m], b0, acc[m][nn], 0, 0, 0);
          }
        }
      }
    }
  }
  long ob = ibase + (long)ty0 * W + tx0 + c15;
  CONV_EPILOGUE_STATS(ob, W, HWl)
}

// ---------------- conv 4x4 s2, +bias +relu — MFMA 3-split, fused staging ----
// IMODE 1: stage = relu(bn(in)+res); IMODE 2: stage = relu(bn(in)+enc_in(x)).
template<int IMODE>
__global__ __launch_bounds__(256) void down_mfma_kernel(
    const float* __restrict__ in, const unsigned short* __restrict__ w0s,
    const unsigned short* __restrict__ w1s, const unsigned short* __restrict__ w2s,
    const float* __restrict__ bias, float* __restrict__ out, int Hin, int Win,
    const float2* __restrict__ mr, const float* __restrict__ res,
    const float* __restrict__ xin, const float* __restrict__ ew,
    const float* __restrict__ eb) {
  __shared__ __align__(16) unsigned short s_x[3][9792];   // [cig2][g4][9*17][8]
  int tid = threadIdx.x, wv = tid >> 6, lane = tid & 63;
  int q = lane >> 4, c15 = lane & 15;
  int Hout = Hin >> 1, Wout = Win >> 1;
  int tilesX = Wout >> 4;
  int tx0 = (blockIdx.x % tilesX) << 4;
  int ty0 = (blockIdx.x / tilesX) << 3;
  int n = blockIdx.z;
  long HWin = (long)Hin * Win, HWout = (long)Hout * Wout;
  long ibase = (long)n * 128 * HWin, obase = (long)n * 128 * HWout;
  f32x4 acc[2][8];
#pragma unroll
  for (int a = 0; a < 2; ++a)
#pragma unroll
    for (int b = 0; b < 8; ++b) acc[a][b] = (f32x4){0.f, 0.f, 0.f, 0.f};

  for (int cc = 0; cc < 8; ++cc) {
    __syncthreads();
    for (int l = tid; l < 1224; l += 256) {
      int cig = l / 612, rem = l % 612;
      int g = rem / 153, p = rem % 153;
      int py = p / 17, px_ = p % 17;
      int gy = g >> 1, gx = g & 1;
      int iy = 2 * (ty0 + py - gy) + gy;
      int ix = 2 * (tx0 + px_ - gx) + gx;
      float v[8];
      if ((unsigned)iy < (unsigned)Hin && (unsigned)ix < (unsigned)Win) {
        int cb0 = cc * 16 + cig * 8;
        const float* ip = in + ibase + (long)cb0 * HWin + (long)iy * Win + ix;
#pragma unroll
        for (int c = 0; c < 8; ++c) v[c] = ip[(long)c * HWin];
        float x0 = 0.f, x1 = 0.f, x2 = 0.f;
        if (IMODE == 2) {
          const float* xp = xin + (long)n * 3 * HWin + (long)iy * Win + ix;
          x0 = xp[0]; x1 = xp[HWin]; x2 = xp[2 * HWin];
        }
        const float* rp = (IMODE == 1)
            ? res + ibase + (long)cb0 * HWin + (long)iy * Win + ix : nullptr;
#pragma unroll
        for (int c = 0; c < 8; ++c) {
          float2 s = mr[cb0 + c];
          float rv;
          if (IMODE == 1) rv = rp[(long)c * HWin];
          else {
            int ci = cb0 + c;
            rv = fmaf(ew[ci * 3 + 0], x0, fmaf(ew[ci * 3 + 1], x1,
                 fmaf(ew[ci * 3 + 2], x2, eb[ci])));
          }
          v[c] = fmaxf((v[c] - s.x) * s.y + rv, 0.f);
        }
      } else {
#pragma unroll
        for (int c = 0; c < 8; ++c) v[c] = 0.f;
      }
      bf16x8 s0, s1, s2;
#pragma unroll
      for (int c = 0; c < 8; ++c) {
        unsigned short h0, h1, h2; split3(v[c], h0, h1, h2);
        s0[c] = (short)h0; s1[c] = (short)h1; s2[c] = (short)h2;
      }
      *(bf16x8*)(s_x[0] + l * 8) = s0;
      *(bf16x8*)(s_x[1] + l * 8) = s1;
      *(bf16x8*)(s_x[2] + l * 8) = s2;
    }
    __syncthreads();

    for (int pr = 0; pr < 8; ++pr) {
      long fbase = (long)((cc * 8 + pr) * 8) * 64;
      bf16x8 a0[2], a1[2], a2[2];
#pragma unroll
      for (int m = 0; m < 2; ++m) {
        long fi = fbase + (2 * wv + m) * 64 + lane;
        a0[m] = ((const bf16x8*)w0s)[fi];
        a1[m] = ((const bf16x8*)w1s)[fi];
        a2[m] = ((const bf16x8*)w2s)[fi];
      }
      int tap = pr * 2 + (q >> 1);
      int ky = tap >> 2, kx = tap & 3;
      int gy = (ky + 1) & 1, gx = (kx + 1) & 1;
      int dy = (ky == 0) ? -1 : ((ky == 3) ? 1 : 0);
      int dx = (kx == 0) ? -1 : ((kx == 3) ? 1 : 0);
      int g = gy * 2 + gx, cig = q & 1;
      int xoff = ((cig * 4 + g) * 153 + (dy + gy) * 17 + (c15 + dx + gx)) * 8;
#pragma unroll
      for (int nn = 0; nn < 8; ++nn) {
        bf16x8 b0 = *(const bf16x8*)(s_x[0] + xoff + nn * 136);
        bf16x8 b1v = *(const bf16x8*)(s_x[1] + xoff + nn * 136);
        bf16x8 b2 = *(const bf16x8*)(s_x[2] + xoff + nn * 136);
#pragma unroll
        for (int m = 0; m < 2; ++m) {
          acc[m][nn] = __builtin_amdgcn_mfma_f32_16x16x32_bf16(a0[m], b0, acc[m][nn], 0, 0, 0);
          acc[m][nn] = __builtin_amdgcn_mfma_f32_16x16x32_bf16(a0[m], b1v, acc[m][nn], 0, 0, 0);
          acc[m][nn] = __builtin_amdgcn_mfma_f32_16x16x32_bf16(a1[m], b0, acc[m][nn], 0, 0, 0);
          acc[m][nn] = __builtin_amdgcn_mfma_f32_16x16x32_bf16(a0[m], b2, acc[m][nn], 0, 0, 0);
          acc[m][nn] = __builtin_amdgcn_mfma_f32_16x16x32_bf16(a1[m], b1v, acc[m][nn], 0, 0, 0);
          acc[m][nn] = __builtin_amdgcn_mfma_f32_16x16x32_bf16(a2[m], b0, acc[m][nn], 0, 0, 0);
        }
      }
    }
  }
#pragma unroll
  for (int mt2 = 0; mt2 < 2; ++mt2) {
    int co0 = (wv * 2 + mt2) * 16 + q * 4;
#pragma unroll
    for (int nn = 0; nn < 8; ++nn) {
      long pxoff = obase + (long)(ty0 + nn) * Wout + tx0 + c15;
#pragma unroll
      for (int r = 0; r < 4; ++r)
        out[pxoff + (long)(co0 + r) * HWout] =
            fmaxf(acc[mt2][nn][r] + bias[co0 + r], 0.f);
    }
  }
}

// ---------------- ConvT 4x4 s2, +bias +relu — MFMA 2-split ------------------
// UMODE 0: raw staging (R10); UMODE 1: stage = relu(bn(in)+res).
template<int UMODE>
__global__ __launch_bounds__(256) void up_mfma_kernel(
    const float* __restrict__ in, const unsigned short* __restrict__ wh,
    const unsigned short* __restrict__ wl, const float* __restrict__ bias,
    float* __restrict__ out, int Hin, int Win,
    const float2* __restrict__ mr, const float* __restrict__ res) {
  __shared__ __align__(16) unsigned short s_xh[5760];   // [cig4][10*18][8]
  __shared__ __align__(16) unsigned short s_xl[5760];
  int tid = threadIdx.x, wv = tid >> 6, lane = tid & 63;
  int q = lane >> 4, c15 = lane & 15;
  int cls = blockIdx.z & 3, n = blockIdx.z >> 2;
  int py = cls >> 1, px = cls & 1;
  int Hout = Hin << 1, Wout = Win << 1;
  int tilesX = Win >> 4;
  int x0 = (blockIdx.x % tilesX) << 4;
  int m0 = (blockIdx.x / tilesX) << 3;
  long HWin = (long)Hin * Win, HWout = (long)Hout * Wout;
  long ibase = (long)n * 128 * HWin, obase = (long)n * 128 * HWout;
  f32x4 acc[2][8];
#pragma unroll
  for (int a = 0; a < 2; ++a)
#pragma unroll
    for (int b = 0; b < 8; ++b) acc[a][b] = (f32x4){0.f, 0.f, 0.f, 0.f};

  for (int cc = 0; cc < 4; ++cc) {
    __syncthreads();
    for (int l = tid; l < 720; l += 256) {
      int cig = l / 180, p = l % 180;
      int y = p / 18, x = p % 18;
      int gy = m0 + y - 1, gx = x0 + x - 1;
      float v[8];
      if ((unsigned)gy < (unsigned)Hin && (unsigned)gx < (unsigned)Win) {
        int cb0 = cc * 32 + cig * 8;
        const float* ip = in + ibase + (long)cb0 * HWin + (long)gy * Win + gx;
#pragma unroll
        for (int c = 0; c < 8; ++c) v[c] = ip[(long)c * HWin];
        if (UMODE == 1) {
          const float* rp = res + ibase + (long)cb0 * HWin + (long)gy * Win + gx;
#pragma unroll
          for (int c = 0; c < 8; ++c) {
            float2 s = mr[cb0 + c];
            v[c] = fmaxf((v[c] - s.x) * s.y + rp[(long)c * HWin], 0.f);
          }
        }
      } else {
#pragma unroll
        for (int c = 0; c < 8; ++c) v[c] = 0.f;
      }
      bf16x8 hv, lv;
#pragma unroll
      for (int c = 0; c < 8; ++c) {
        unsigned short h = f2bf(v[c]);
        hv[c] = (short)h;
        lv[c] = (short)f2bf(v[c] - bf2f(h));
      }
      *(bf16x8*)(s_xh + l * 8) = hv;
      *(bf16x8*)(s_xl + l * 8) = lv;
    }
    __syncthreads();

#pragma unroll
    for (int j = 0; j < 4; ++j) {
      int jy = j >> 1, jx = j & 1;
      int dy = py ? (jy ? 0 : 1) : (jy ? -1 : 0);
      int dx = px ? (jx ? 0 : 1) : (jx ? -1 : 0);
      long fbase = (long)((((cc * 4 + cls) * 4 + j) * 8)) * 64;
      const bf16x8* aph = (const bf16x8*)wh + fbase;
      const bf16x8* apl = (const bf16x8*)wl + fbase;
      bf16x8 ah0 = aph[(2 * wv) * 64 + lane];
      bf16x8 ah1 = aph[(2 * wv + 1) * 64 + lane];
      bf16x8 al0 = apl[(2 * wv) * 64 + lane];
      bf16x8 al1 = apl[(2 * wv + 1) * 64 + lane];
      int xoff = (q * 180 + (dy + 1) * 18 + (c15 + dx + 1)) * 8;
#pragma unroll
      for (int nn = 0; nn < 8; ++nn) {
        bf16x8 bh = *(const bf16x8*)(s_xh + xoff + nn * 144);
        bf16x8 bl = *(const bf16x8*)(s_xl + xoff + nn * 144);
        acc[0][nn] = __builtin_amdgcn_mfma_f32_16x16x32_bf16(ah0, bh, acc[0][nn], 0, 0, 0);
        acc[0][nn] = __builtin_amdgcn_mfma_f32_16x16x32_bf16(ah0, bl, acc[0][nn], 0, 0, 0);
        acc[0][nn] = __builtin_amdgcn_mfma_f32_16x16x32_bf16(al0, bh, acc[0][nn], 0, 0, 0);
        acc[1][nn] = __builtin_amdgcn_mfma_f32_16x16x32_bf16(ah1, bh, acc[1][nn], 0, 0, 0);
        acc[1][nn] = __builtin_amdgcn_mfma_f32_16x16x32_bf16(ah1, bl, acc[1][nn], 0, 0, 0);
        acc[1][nn] = __builtin_amdgcn_mfma_f32_16x16x32_bf16(al1, bh, acc[1][nn], 0, 0, 0);
      }
    }
  }
#pragma unroll
  for (int mt2 = 0; mt2 < 2; ++mt2) {
    int co0 = (wv * 2 + mt2) * 16 + q * 4;
#pragma unroll
    for (int nn = 0; nn < 8; ++nn) {
      long pxoff = obase + (long)(2 * (m0 + nn) + py) * Wout + 2 * (x0 + c15) + px;
#pragma unroll
      for (int r = 0; r < 4; ++r)
        out[pxoff + (long)(co0 + r) * HWout] =
            fmaxf(acc[mt2][nn][r] + bias[co0 + r], 0.f);
    }
  }
}

// ---------------- conv 1x1 (+bias, ACT: 0=none, 2=sigmoid) ----------------
template<int ACT, int CW>
__global__ __launch_bounds__(256) void conv1x1_kernel(
    const float* __restrict__ in, const float* __restrict__ w,
    const float* __restrict__ bias, float* __restrict__ out,
    int N, int Cin, int Cout, int HW) {
  extern __shared__ float wl[];
  int co0 = blockIdx.y * CW;
  for (int i = threadIdx.x; i < CW * Cin; i += blockDim.x)
    wl[i] = w[(long)co0 * Cin + i];
  __syncthreads();
  int HW4 = HW >> 2;
  long p4 = (long)blockIdx.x * blockDim.x + threadIdx.x;
  if (p4 >= (long)N * HW4) return;
  int n = (int)(p4 / HW4), hw4 = (int)(p4 % HW4);
  const float4* inp = (const float4*)(in + (long)n * Cin * HW) + hw4;
  float4* outp = (float4*)(out + (long)n * Cout * HW) + hw4;
  float4 acc[CW];
#pragma unroll
  for (int j = 0; j < CW; ++j) { float bb = bias[co0 + j]; acc[j] = make_float4(bb, bb, bb, bb); }
  for (int ci = 0; ci < Cin; ++ci) {
    float4 v = inp[(long)ci * HW4];
#pragma unroll
    for (int j = 0; j < CW; ++j) {
      float ww = wl[j * Cin + ci];
      acc[j].x = fmaf(ww, v.x, acc[j].x);
      acc[j].y = fmaf(ww, v.y, acc[j].y);
      acc[j].z = fmaf(ww, v.z, acc[j].z);
      acc[j].w = fmaf(ww, v.w, acc[j].w);
    }
  }
#pragma unroll
  for (int j = 0; j < CW; ++j) {
    float4 v = acc[j];
    if (ACT == 2) {
      v.x = 1.f / (1.f + expf(-v.x));
      v.y = 1.f / (1.f + expf(-v.y));
      v.z = 1.f / (1.f + expf(-v.z));
      v.w = 1.f / (1.f + expf(-v.w));
    }
    outp[(long)(co0 + j) * HW4] = v;
  }
}

// ---------------- BN finalize (reads part, writes mr, zeroes part) ----------
__global__ __launch_bounds__(128) void bn_final_kernel(
    double* __restrict__ part, float2* __restrict__ mr, float cntf) {
  int c = threadIdx.x;
  double s = 0.0, ss = 0.0;
#pragma unroll
  for (int sl = 0; sl < 8; ++sl) {
    s  += part[(sl * 128 + c) * 2 + 0];
    ss += part[(sl * 128 + c) * 2 + 1];
  }
  double cnt = (double)cntf;
  double m = s / cnt;
  double var = ss / cnt - m * m;
  mr[c] = make_float2((float)m, (float)(1.0 / sqrt(var + 1e-5)));
#pragma unroll
  for (int sl = 0; sl < 8; ++sl) {
    part[(sl * 128 + c) * 2 + 0] = 0.0;
    part[(sl * 128 + c) * 2 + 1] = 0.0;
  }
}

// ---------------- in-place: y = relu(bn(y) + residual) ----------------------
__global__ __launch_bounds__(256) void bn_res_relu_kernel(
    float* __restrict__ y, const float2* __restrict__ mr,
    const float* __restrict__ res, int HW4) {
  int nc = blockIdx.y;
  int c = nc & 127;
  float2 s = mr[c];
  int i = blockIdx.x * blockDim.x + threadIdx.x;
  if (i >= HW4) return;
  long off = (long)nc * HW4 + i;
  float4 v = ((const float4*)y)[off];
  float4 r4 = ((const float4*)res)[off];
  v.x = fmaxf((v.x - s.x) * s.y + r4.x, 0.f);
  v.y = fmaxf((v.y - s.x) * s.y + r4.y, 0.f);
  v.z = fmaxf((v.z - s.x) * s.y + r4.z, 0.f);
  v.w = fmaxf((v.w - s.x) * s.y + r4.w, 0.f);
  ((float4*)y)[off] = v;
}

// ---------------- VQ (R10-proven) -------------------------------------------
__global__ __launch_bounds__(256) void vq_kernel(
    const float* __restrict__ z, const float* __restrict__ cb,
    float* __restrict__ idx_out, float* __restrict__ counts, int HWl) {
  __shared__ float s_z[64][65];
  __shared__ float s_cb[64][64];
  __shared__ float s_bd[4][64];
  __shared__ int   s_bk[4][64];
  int tid = threadIdx.x;
  int r0 = blockIdx.x * 64;
  for (int l = tid; l < 64 * 64; l += 256) {
    int c = l >> 6, rs = l & 63;
    int r = r0 + rs;
    int n = r / HWl, rem = r % HWl;
    s_z[rs][c] = z[((long)(n * 64 + c)) * HWl + rem];
  }
  int row = tid & 63, cg = tid >> 6;
  float best = 3.4e38f; int bestk = 0;
  for (int k0 = 0; k0 < 1024; k0 += 64) {
    __syncthreads();
    for (int l = tid; l < 4096; l += 256)
      s_cb[l >> 6][l & 63] = cb[(long)(k0 + (l >> 6)) * 64 + (l & 63)];
    __syncthreads();
#pragma unroll
    for (int j = 0; j < 16; ++j) {
      int kk = cg * 16 + j;
      const float* zp = s_z[row];
      const float* cp = s_cb[kk];
      float d = 0.f;
#pragma unroll
      for (int c = 0; c < 64; ++c) {
        float t = zp[c] - cp[c];
        d = fmaf(t, t, d);
      }
      int k = k0 + kk;
      if (d < best) { best = d; bestk = k; }
    }
  }
  s_bd[cg][row] = best; s_bk[cg][row] = bestk;
  __syncthreads();
  if (tid < 64) {
    float bd = s_bd[0][tid]; int bk = s_bk[0][tid];
#pragma unroll
    for (int g = 1; g < 4; ++g) {
      float d2 = s_bd[g][tid]; int k2 = s_bk[g][tid];
      if (d2 < bd || (d2 == bd && k2 < bk)) { bd = d2; bk = k2; }
    }
    idx_out[r0 + tid] = (float)bk;
    atomicAdd(&counts[bk], 1.0f);
  }
}

// ---------------- zero small buffer ----------------------------------------
__global__ __launch_bounds__(256) void zero_kernel(float* __restrict__ p, int n) {
  int i = blockIdx.x * 256 + threadIdx.x;
  if (i < n) p[i] = 0.f;
}

// ---------------- loss = sum p log p ----------------------------------------
__global__ __launch_bounds__(256) void entropy_kernel(
    const float* __restrict__ counts, float* __restrict__ loss_out) {
  __shared__ double sh[256];
  int tid = threadIdx.x;
  double s = 0.0;
  for (int i = tid; i < 1024; i += 256) s += (double)counts[i] + 1e-6;
  sh[tid] = s; __syncthreads();
  for (int off = 128; off > 0; off >>= 1) {
    if (tid < off) sh[tid] += sh[tid + off];
    __syncthreads();
  }
  double S = sh[0];
  __syncthreads();
  double pl = 0.0;
  for (int i = tid; i < 1024; i += 256) {
    double p = ((double)counts[i] + 1e-6) / S;
    pl += p * log(p);
  }
  sh[tid] = pl; __syncthreads();
  for (int off = 128; off > 0; off >>= 1) {
    if (tid < off) sh[tid] += sh[tid + off];
    __syncthreads();
  }
  if (tid == 0) loss_out[0] = (float)sh[0];
}

// ---------------------------------------------------------------------------
extern "C" void kernel_launch(void* const* d_in, const int* in_sizes, int n_in,
                              void* d_out, int out_size, void* d_ws, size_t ws_size,
                              hipStream_t stream) {
  (void)in_sizes; (void)n_in; (void)out_size; (void)ws_size;
  const float* x          = (const float*)d_in[0];
  const float* enc_in_w   = (const float*)d_in[1];
  const float* enc_in_b   = (const float*)d_in[2];
  const float* enc_res_w1 = (const float*)d_in[3];
  const float* enc_res_b1 = (const float*)d_in[4];
  const float* enc_res_w2 = (const float*)d_in[5];
  const float* enc_res_b2 = (const float*)d_in[6];
  const float* enc_down_w = (const float*)d_in[7];
  const float* enc_down_b = (const float*)d_in[8];
  const float* enc_out_w  = (const float*)d_in[9];
  const float* enc_out_b  = (const float*)d_in[10];
  const float* dec_in_w   = (const float*)d_in[11];
  const float* dec_in_b   = (const float*)d_in[12];
  const float* dec_res_w1 = (const float*)d_in[13];
  const float* dec_res_b1 = (const float*)d_in[14];
  const float* dec_res_w2 = (const float*)d_in[15];
  const float* dec_res_b2 = (const float*)d_in[16];
  const float* dec_up_w   = (const float*)d_in[17];
  const float* dec_up_b   = (const float*)d_in[18];
  const float* dec_out_w  = (const float*)d_in[19];
  const float* dec_out_b  = (const float*)d_in[20];
  const float* codebook   = (const float*)d_in[21];
  float* out = (float*)d_out;

  const long BIG = 33554432;
  const long S1 = 8388608, S2 = 16777216, S3 = 25165824;
  float* P0 = (float*)d_ws;
  float* P1 = P0 + BIG;
  // d_out scratch (all < RE_SIZE; recon overwrites at the very end):
  float2* mr   = (float2*)out;                          // [0,256)
  float* hist  = out + 256;                             // [256,1280)
  double* part = (double*)(out + 1280);                 // 8sl*128*2 dbl [1280,5376)
  unsigned short* W0 = (unsigned short*)(out + 8192);
  unsigned short* W1 = (unsigned short*)(out + 139264);
  unsigned short* W2 = (unsigned short*)(out + 270336);
  unsigned short* F0 = (unsigned short*)(out + 401408);
  unsigned short* F1 = F0 + 8192;
  unsigned short* F2 = F1 + 8192;

  const int W3 = 128 * 128 * 9, W4 = 128 * 128 * 16, BS = 128;
  const dim3 g256(512, 1, 4), g128(128, 1, 4), g64(32, 1, 4);

  // zero hist + part (4096 floats of doubles)
  zero_kernel<<<20, 256, 0, stream>>>(out + 256, 5120);

  // ===================== encoder (SPLIT=3, fp32-class) =====================
  weff_kernel<<<32, 256, 0, stream>>>(enc_res_w1, enc_in_w, enc_in_b, F0, F1, F2);
  conv36_mfma_kernel<<<g256, 256, 0, stream>>>(
      x, F0, F1, F2, enc_res_b1, P0, part, 256, 256);
  bn_final_kernel<<<1, 128, 0, stream>>>(part, mr, 262144.f);
  wsplit_kernel<<<576, 256, 0, stream>>>(enc_res_w2, W0, W1, W2);
  conv3x3_mfma_kernel<1, 3><<<g256, 256, 0, stream>>>(
      P0, W0, W1, W2, enc_res_b2, P1, 256, 256, mr, part);
  bn_final_kernel<<<1, 128, 0, stream>>>(part, mr, 262144.f);
  wsplit4_kernel<<<1024, 256, 0, stream>>>(enc_down_w, W0, W1, W2);
  // down0: stage = relu(bn(P1) + enc_in(x)); out -> P0[0:S1)
  down_mfma_kernel<2><<<g128, 256, 0, stream>>>(
      P1, W0, W1, W2, enc_down_b, P0, 256, 256, mr, nullptr, x, enc_in_w, enc_in_b);

  wsplit_kernel<<<576, 256, 0, stream>>>(enc_res_w1 + W3, W0, W1, W2);
  conv3x3_mfma_kernel<0, 3><<<g128, 256, 0, stream>>>(
      P0, W0, W1, W2, enc_res_b1 + BS, P0 + S1, 128, 128, nullptr, part);
  bn_final_kernel<<<1, 128, 0, stream>>>(part, mr, 65536.f);
  wsplit_kernel<<<576, 256, 0, stream>>>(enc_res_w2 + W3, W0, W1, W2);
  conv3x3_mfma_kernel<1, 3><<<g128, 256, 0, stream>>>(
      P0 + S1, W0, W1, W2, enc_res_b2 + BS, P0 + S2, 128, 128, mr, part);
  bn_final_kernel<<<1, 128, 0, stream>>>(part, mr, 65536.f);
  wsplit4_kernel<<<1024, 256, 0, stream>>>(enc_down_w + W4, W0, W1, W2);
  // down1: stage = relu(bn(P0+S2) + P0); out -> P0+S3
  down_mfma_kernel<1><<<g64, 256, 0, stream>>>(
      P0 + S2, W0, W1, W2, enc_down_b + BS, P0 + S3, 128, 128, mr, P0,
      nullptr, nullptr, nullptr);

  conv1x1_kernel<0, 16><<<dim3(16, 4), 256, 16 * 128 * 4, stream>>>(
      P0 + S3, enc_out_w, enc_out_b, P1, 4, 128, 64, 4096);

  // ===================== VQ =====================
  vq_kernel<<<256, 256, 0, stream>>>(P1, codebook, out + RE_SIZE + 1, hist, 4096);
  entropy_kernel<<<1, 256, 0, stream>>>(hist, out + RE_SIZE);

  // ===================== decoder (SPLIT=2) =====================
  conv1x1_kernel<0, 16><<<dim3(16, 8), 256, 16 * 64 * 4, stream>>>(
      P1, dec_in_w, dec_in_b, P0, 4, 64, 128, 4096);

  wsplit_kernel<<<576, 256, 0, stream>>>(dec_res_w1, W0, W1, W2);
  conv3x3_mfma_kernel<0, 2><<<g64, 256, 0, stream>>>(
      P0, W0, W1, W2, dec_res_b1, P0 + S1, 64, 64, nullptr, part);
  bn_final_kernel<<<1, 128, 0, stream>>>(part, mr, 16384.f);
  wsplit_kernel<<<576, 256, 0, stream>>>(dec_res_w2, W0, W1, W2);
  conv3x3_mfma_kernel<1, 2><<<g64, 256, 0, stream>>>(
      P0 + S1, W0, W1, W2, dec_res_b2, P0 + S2, 64, 64, mr, part);
  bn_final_kernel<<<1, 128, 0, stream>>>(part, mr, 16384.f);
  wsplitT_kernel<<<1024, 256, 0, stream>>>(dec_up_w, W0, W1);
  // up0: stage = relu(bn(P0+S2) + P0); out -> P0+S3 (no overlap)
  up_mfma_kernel<1><<<dim3(32, 1, 16), 256, 0, stream>>>(
      P0 + S2, W0, W1, dec_up_b, P0 + S3, 64, 64, mr, P0);

  wsplit_kernel<<<576, 256, 0, stream>>>(dec_res_w1 + W3, W0, W1, W2);
  conv3x3_mfma_kernel<0, 2><<<g128, 256, 0, stream>>>(
      P0 + S3, W0, W1, W2, dec_res_b1 + BS, P1, 128, 128, nullptr, part);
  bn_final_kernel<<<1, 128, 0, stream>>>(part, mr, 65536.f);
  wsplit_kernel<<<576, 256, 0, stream>>>(dec_res_w2 + W3, W0, W1, W2);
  conv3x3_mfma_kernel<1, 2><<<g128, 256, 0, stream>>>(
      P1, W0, W1, W2, dec_res_b2 + BS, P1 + S1, 128, 128, mr, part);
  bn_final_kernel<<<1, 128, 0, stream>>>(part, mr, 65536.f);
  // up1 input: in-place bn+res (no alias-free region for fused-out variant)
  bn_res_relu_kernel<<<dim3(16, 512), 256, 0, stream>>>(
      P1 + S1, mr, P0 + S3, 4096);
  wsplitT_kernel<<<1024, 256, 0, stream>>>(dec_up_w + W4, W0, W1);
  up_mfma_kernel<0><<<dim3(128, 1, 16), 256, 0, stream>>>(
      P1 + S1, W0, W1, dec_up_b + BS, P0, 128, 128, nullptr, nullptr);

  conv1x1_kernel<2, 3><<<dim3(256, 1), 256, 3 * 128 * 4, stream>>>(
      P0, dec_out_w, dec_out_b, out, 4, 128, 3, 65536);
}